// Round 14
// baseline (76.864 us; speedup 1.0000x reference)
//
#include <hip/hip_runtime.h>

#define NB 32768
#define GPB 8
#define THREADS 256
#define BIAS_SP 0.5413248546129181f

typedef __attribute__((ext_vector_type(8))) short bf16x8;
typedef __attribute__((ext_vector_type(4))) float f32x4;
typedef __attribute__((ext_vector_type(4))) unsigned int u32x4;

static __device__ __forceinline__ unsigned f2bfu(float f) {
    union { float f; unsigned u; } v; v.f = f;
    return (v.u + 0x8000u) >> 16;
}
static __device__ __forceinline__ float lof(unsigned u) {
    union { unsigned u; float f; } v; v.u = u << 16; return v.f;
}
static __device__ __forceinline__ float hif(unsigned u) {
    union { unsigned u; float f; } v; v.u = u & 0xFFFF0000u; return v.f;
}
static __device__ __forceinline__ float fast_tanh(float xx) {
    float e = __expf(2.0f * xx);
    return 1.0f - 2.0f * __builtin_amdgcn_rcpf(e + 1.0f);
}
// D[15:0]=bf16(S0), D[31:16]=bf16(S1). Output MUST be a plain unsigned lvalue
// (asm output into an ext_vector element propagated undef -> NaN, R11 lesson).
#define CVTPK(d, a, b) asm("v_cvt_pk_bf16_f32 %0, %1, %2" : "=v"(d) : "v"(a), "v"(b))

// Adjacency row-masks: bit m of SMASK[n] = edge (m -> n). Row 15 (pad) = 0.
__constant__ unsigned short SMASK[16] = {
    0x000E, 0x0001, 0x0001, 0x0071, 0x0008, 0x0008, 0x0388, 0x0040,
    0x0040, 0x1C40, 0x0200, 0x0200, 0x6200, 0x1000, 0x1000, 0x0000
};

// ---------------------------------------------------------------------------
// Setup: ws (dwords):
//   [0,12288)      conv B-frags: s=0,1 Wroot k0-63, s=2,3 Wrel k0-63
//   [12288,14080)  head weights (bf16 [item][k])
//   [14080,15104)  encoder B-frag: K-rows = [Wt(8); Wl(4); bt; bl; 0..]
// ---------------------------------------------------------------------------
__global__ void setup_kernel(const float* __restrict__ Wroot, const float* __restrict__ Wrel,
                             const float* __restrict__ legW, const float* __restrict__ torW,
                             const float* __restrict__ Wt, const float* __restrict__ bt,
                             const float* __restrict__ Wl, const float* __restrict__ bl,
                             unsigned* __restrict__ wsw) {
    const int t = blockIdx.x * 256 + threadIdx.x;
    if (t < 3072) {                       // conv B-fragments
        const int i = t >> 10, rem = t & 1023, s = rem >> 8, tt = rem & 255;
        const int lane = tt & 63, ctl = tt >> 6;
        const int bcol = (ctl << 4) + (lane & 15);
        const int kb = ((s & 1) << 5) + ((lane >> 4) << 3);
        const float* M = ((s < 2) ? Wroot : Wrel) + i * 4096 + kb * 64 + bcol;
        u32x4 d;
        #pragma unroll
        for (int dd = 0; dd < 4; ++dd)
            d[dd] = f2bfu(M[(2 * dd) * 64]) | (f2bfu(M[(2 * dd + 1) * 64]) << 16);
        *(u32x4*)(wsw + t * 4) = d;
    } else if (t < 3520) {                // head weights
        const int t2 = t - 3072, item = t2 >> 3, k8 = t2 & 7;
        const int p = (item >> 2) + 1, j = item & 3;
        const int p3 = (p * 11) >> 5;
        const int pm3 = p - p3 * 3;
        const float* src;
        if (pm3 == 0) src = torW + (p3 - 1) * 256 + j;
        else          src = legW + (2 * p3 + pm3 - 1) * 256 + j;
        u32x4 d;
        #pragma unroll
        for (int dd = 0; dd < 4; ++dd) {
            const int k = (k8 << 3) + 2 * dd;
            d[dd] = f2bfu(src[k * 4]) | (f2bfu(src[(k + 1) * 4]) << 16);
        }
        *(u32x4*)(wsw + 12288 + t2 * 4) = d;
    } else if (t < 3776) {                // encoder B-fragment
        const int t3 = t - 3520;
        const int lane = t3 & 63, ctl = t3 >> 6;
        const int col = (ctl << 4) + (lane & 15);
        const int kg = lane >> 4;
        auto encval = [&](int k) -> float {
            if (k < 8)   return Wt[k * 64 + col];
            if (k < 12)  return Wl[(k - 8) * 64 + col];
            if (k == 12) return bt[col];
            if (k == 13) return bl[col];
            return 0.f;
        };
        u32x4 d;
        #pragma unroll
        for (int dd = 0; dd < 4; ++dd) {
            const int k0 = kg * 8 + 2 * dd;
            d[dd] = f2bfu(encval(k0)) | (f2bfu(encval(k0 + 1)) << 16);
        }
        *(u32x4*)(wsw + 14080 + t3 * 4) = d;
    }
}

// ---------------------------------------------------------------------------
// Main (R12, best verified): AGG-free MFMA chain.
// out = tanh(S*(h@Wrel) + h@Wroot + b). S held as constant A-fragment
// (4 VGPRs, zero-interleaved into K=32); U = h@Wrel C-layout == B-operand
// layout of the S-MFMA -> aggregation is zero-LDS. LDS/graph: 2KB h only,
// swizzle slot ^= row&7; bank conflicts measured 0.
// launch_bounds(256,4): KEEP. (256,8) caused a 91us regression AND a
// post-timing output divergence (R13, mechanism unidentified) - poisoned.
// ---------------------------------------------------------------------------
__global__ __launch_bounds__(THREADS, 4) void leg_main(
    const float* __restrict__ x,
    const float* __restrict__ gcb,
    const float* __restrict__ legB, const float* __restrict__ torB,
    const unsigned* __restrict__ wsw,
    float* __restrict__ out)
{
    __shared__ __align__(16) unsigned char smem[GPB * 2048];
    const int tid  = threadIdx.x;
    const int lane = tid & 63;
    const int ct   = tid >> 6;                 // wave id = col-tile
    const int g0   = blockIdx.x * GPB;

    const int bcol = (ct << 4) + (lane & 15);
    const float cb0 = gcb[bcol], cb1 = gcb[64 + bcol], cb2 = gcb[128 + bcol];

    // --- per-lane LDS byte offsets (2KB tiles: row stride 128B, 8 slots) ---
    const int row = lane & 15, kg = lane >> 4;
    const int voffA0 = row * 128 + (((kg ^ row) & 7) << 4);   // h k0-31
    const int voffA1 = voffA0 ^ 0x40;                         // h k32-63
    int voffC[4];
    #pragma unroll
    for (int r = 0; r < 4; ++r) {
        const int rr = (kg << 2) + r;
        voffC[r] = rr * 128 + (((((ct << 1) + ((lane >> 3) & 1)) ^ rr) & 7) << 4) + ((lane & 7) << 1);
    }

    // --- constant S' A-fragment from adjacency table (row 15 mask = 0) ---
    const unsigned sm = SMASK[row];
    union { u32x4 u; bf16x8 b; } sf;
    #pragma unroll
    for (int j2 = 0; j2 < 4; ++j2)
        sf.u[j2] = ((sm >> ((kg << 2) + j2)) & 1) ? 0x3F80u : 0u;  // bf16 1.0 at even k

// epilogue: tanh(acc[g]) -> bf16 -> LDS h (all 4 layers share)
#define EPI() do { \
    _Pragma("unroll") for (int g = 0; g < GPB; ++g) { \
        _Pragma("unroll") for (int r = 0; r < 4; ++r) { \
            const float tv = fast_tanh(acc[g][r]); \
            unsigned uu; CVTPK(uu, tv, tv); \
            *(unsigned short*)(smem + g * 2048 + voffC[r]) = (unsigned short)uu; \
        } } } while (0)

    // --- encoder (layer 0) as MFMA: A = [isT*x(8) | isL*x(0:4) | isT | isL] ---
    const int nmod3 = row - ((row * 11) >> 5) * 3;
    const bool nT = (nmod3 == 0);
    const unsigned mT = (nT && row < 15) ? 0xFFFFFFFFu : 0u;
    const unsigned mL = nT ? 0u : 0xFFFFFFFFu;
    const unsigned m01 = (kg == 0) ? mT : ((kg == 1) ? mL : 0u);
    const unsigned m45 = (kg == 0) ? mT : 0u;
    const unsigned c1213 = (kg == 1) ? ((mT ? 0x3F80u : 0u) | (mL ? 0x3F800000u : 0u)) : 0u;
    const int rowc = (row < 15) ? row : 0;
    const bf16x8 bfrE = *(const bf16x8*)(wsw + 14080 + tid * 4);

    f32x4 acc[GPB];
    #pragma unroll
    for (int g = 0; g < GPB; ++g) {
        const float4* xr = (const float4*)x + ((size_t)(g0 + g) * 15 + rowc) * 2;
        const float4 x0 = xr[0], x1 = xr[1];
        unsigned a01, a23, a45, a67;
        CVTPK(a01, x0.x, x0.y); CVTPK(a23, x0.z, x0.w);
        CVTPK(a45, x1.x, x1.y); CVTPK(a67, x1.z, x1.w);
        union { u32x4 u; bf16x8 b; } af;
        af.u[0] = a01 & m01;
        af.u[1] = a23 & m01;
        af.u[2] = (a45 & m45) | c1213;
        af.u[3] = a67 & m45;
        const f32x4 z = { 0.f, 0.f, 0.f, 0.f };
        acc[g] = __builtin_amdgcn_mfma_f32_16x16x32_bf16(af.b, bfrE, z, 0, 0, 0);
    }
    EPI();                   // waves write disjoint col-tiles
    __syncthreads();         // h0 visible to all waves' A-reads

    // --- 3x GraphConv: V = h@Wroot + b; U = h@Wrel; out = S'*U' + V ---
    #pragma unroll
    for (int it = 0; it < 3; ++it) {
        bf16x8 bfr[4];       // 0,1: Wroot k0-31,k32-63; 2,3: Wrel
        #pragma unroll
        for (int s = 0; s < 4; ++s)
            bfr[s] = *(const bf16x8*)(wsw + ((it * 4 + s) * 256 + tid) * 4);
        const float cbi = (it == 0) ? cb0 : (it == 1) ? cb1 : cb2;
        #pragma unroll
        for (int g = 0; g < GPB; ++g) {
            const unsigned char* sg = smem + g * 2048;
            const bf16x8 a0 = *(const bf16x8*)(sg + voffA0);
            const bf16x8 a1 = *(const bf16x8*)(sg + voffA1);
            f32x4 V = { cbi, cbi, cbi, cbi };
            V = __builtin_amdgcn_mfma_f32_16x16x32_bf16(a0, bfr[0], V, 0, 0, 0);
            V = __builtin_amdgcn_mfma_f32_16x16x32_bf16(a1, bfr[1], V, 0, 0, 0);
            const f32x4 z = { 0.f, 0.f, 0.f, 0.f };
            f32x4 U;
            U = __builtin_amdgcn_mfma_f32_16x16x32_bf16(a0, bfr[2], z, 0, 0, 0);
            U = __builtin_amdgcn_mfma_f32_16x16x32_bf16(a1, bfr[3], U, 0, 0, 0);
            // U' B-frag: k-slot kg*8+2r holds bf16(U[r]) low half, 0 high.
            union { u32x4 u; bf16x8 b; } ub;
            ub.u[0] = f2bfu(U[0]);
            ub.u[1] = f2bfu(U[1]);
            ub.u[2] = f2bfu(U[2]);
            ub.u[3] = f2bfu(U[3]);
            acc[g] = __builtin_amdgcn_mfma_f32_16x16x32_bf16(sf.b, ub.b, V, 0, 0, 0);
        }
        __syncthreads();     // all A-reads done before EPI overwrites h
        EPI();
        __syncthreads();     // new h visible
    }

    // --- heads: wave ct -> graphs 2ct, 2ct+1; lane = (p,j) item ---
    // unpack-FMA path (proven). No raw-asm dot2 (R3/R4 lesson).
    if (lane < 56) {
        const int p = (lane >> 2) + 1, j = lane & 3;
        const int p3 = (p * 11) >> 5;
        const int pm3 = p - p3 * 3;
        float bias;
        if (pm3 == 0) bias = torB[((p3 - 1) << 2) + j];
        else          bias = legB[(((p3 << 1) + pm3 - 1) << 2) + j];
        const unsigned* wp = wsw + 12288 + (lane << 5);
        const int ps = (p & 7) << 4;
        #pragma unroll
        for (int gs = 0; gs < 2; ++gs) {
            const int g = (ct << 1) + gs;
            const unsigned char* hb = smem + g * 2048 + p * 128;
            float acch = 0.f;
            #pragma unroll
            for (int k8 = 0; k8 < 8; ++k8) {
                const u32x4 hv = *(const u32x4*)(hb + (ps ^ (k8 << 4)));
                const u32x4 wv = *(const u32x4*)(wp + (k8 << 2));
                #pragma unroll
                for (int dd = 0; dd < 4; ++dd) {
                    acch = __builtin_fmaf(lof(hv[dd]), lof(wv[dd]), acch);
                    acch = __builtin_fmaf(hif(hv[dd]), hif(wv[dd]), acch);
                }
            }
            acch += bias;
            const int mloc = ((p - 1) << 1) + (j >> 1);
            const size_t ob = (size_t)(g0 + g) * 28 + mloc;
            if ((j & 1) == 0) {
                out[ob] = acch;
            } else {
                const float z = acch + BIAS_SP;
                const float sp = (z > 15.f) ? z : __logf(1.f + __expf(z));
                out[(size_t)NB * 28 + ob] = fmaxf(sp, 1e-4f);
            }
        }
    }
}

extern "C" void kernel_launch(void* const* d_in, const int* in_sizes, int n_in,
                              void* d_out, int out_size, void* d_ws, size_t ws_size,
                              hipStream_t stream) {
    (void)in_sizes; (void)n_in; (void)out_size; (void)ws_size;
    const float* x     = (const float*)d_in[0];
    // d_in[1] = edge_index (fixed template, unused), d_in[2] = batch_size
    const float* Wt    = (const float*)d_in[3];
    const float* bt    = (const float*)d_in[4];
    const float* Wl    = (const float*)d_in[5];
    const float* bl    = (const float*)d_in[6];
    const float* Wroot = (const float*)d_in[7];
    const float* Wrel  = (const float*)d_in[8];
    const float* gcb   = (const float*)d_in[9];
    const float* legW  = (const float*)d_in[10];
    const float* legB  = (const float*)d_in[11];
    const float* torW  = (const float*)d_in[12];
    const float* torB  = (const float*)d_in[13];
    unsigned* wsw = (unsigned*)d_ws;           // needs 60416 B of scratch
    setup_kernel<<<15, 256, 0, stream>>>(Wroot, Wrel, legW, torW, Wt, bt, Wl, bl, wsw);
    leg_main<<<NB / GPB, THREADS, 0, stream>>>(x, gcb, legB, torB, wsw, (float*)d_out);
}

// Round 15
// 75.411 us; speedup vs baseline: 1.0193x; 1.0193x over previous
//
#include <hip/hip_runtime.h>

#define NB 32768
#define GPB 16
#define THREADS 256
#define BIAS_SP 0.5413248546129181f

typedef __attribute__((ext_vector_type(8))) short bf16x8;
typedef __attribute__((ext_vector_type(4))) float f32x4;
typedef __attribute__((ext_vector_type(4))) unsigned int u32x4;

static __device__ __forceinline__ unsigned f2bfu(float f) {
    union { float f; unsigned u; } v; v.f = f;
    return (v.u + 0x8000u) >> 16;
}
static __device__ __forceinline__ float lof(unsigned u) {
    union { unsigned u; float f; } v; v.u = u << 16; return v.f;
}
static __device__ __forceinline__ float hif(unsigned u) {
    union { unsigned u; float f; } v; v.u = u & 0xFFFF0000u; return v.f;
}
static __device__ __forceinline__ float fast_tanh(float xx) {
    float e = __expf(2.0f * xx);
    return 1.0f - 2.0f * __builtin_amdgcn_rcpf(e + 1.0f);
}
// D[15:0]=bf16(S0), D[31:16]=bf16(S1). Output MUST be a plain unsigned lvalue
// (asm output into an ext_vector element propagated undef -> NaN, R11 lesson).
#define CVTPK(d, a, b) asm("v_cvt_pk_bf16_f32 %0, %1, %2" : "=v"(d) : "v"(a), "v"(b))

// Adjacency row-masks: bit m of SMASK[n] = edge (m -> n). Row 15 (pad) = 0.
__constant__ unsigned short SMASK[16] = {
    0x000E, 0x0001, 0x0001, 0x0071, 0x0008, 0x0008, 0x0388, 0x0040,
    0x0040, 0x1C40, 0x0200, 0x0200, 0x6200, 0x1000, 0x1000, 0x0000
};

// ---------------------------------------------------------------------------
// Setup (unchanged): ws (dwords):
//   [0,12288)      conv B-frags: s=0,1 Wroot k0-63, s=2,3 Wrel k0-63
//   [12288,14080)  head weights (bf16 [item][k])
//   [14080,15104)  encoder B-frag: K-rows = [Wt(8); Wl(4); bt; bl; 0..]
// ---------------------------------------------------------------------------
__global__ void setup_kernel(const float* __restrict__ Wroot, const float* __restrict__ Wrel,
                             const float* __restrict__ legW, const float* __restrict__ torW,
                             const float* __restrict__ Wt, const float* __restrict__ bt,
                             const float* __restrict__ Wl, const float* __restrict__ bl,
                             unsigned* __restrict__ wsw) {
    const int t = blockIdx.x * 256 + threadIdx.x;
    if (t < 3072) {                       // conv B-fragments
        const int i = t >> 10, rem = t & 1023, s = rem >> 8, tt = rem & 255;
        const int lane = tt & 63, ctl = tt >> 6;
        const int bcol = (ctl << 4) + (lane & 15);
        const int kb = ((s & 1) << 5) + ((lane >> 4) << 3);
        const float* M = ((s < 2) ? Wroot : Wrel) + i * 4096 + kb * 64 + bcol;
        u32x4 d;
        #pragma unroll
        for (int dd = 0; dd < 4; ++dd)
            d[dd] = f2bfu(M[(2 * dd) * 64]) | (f2bfu(M[(2 * dd + 1) * 64]) << 16);
        *(u32x4*)(wsw + t * 4) = d;
    } else if (t < 3520) {                // head weights
        const int t2 = t - 3072, item = t2 >> 3, k8 = t2 & 7;
        const int p = (item >> 2) + 1, j = item & 3;
        const int p3 = (p * 11) >> 5;
        const int pm3 = p - p3 * 3;
        const float* src;
        if (pm3 == 0) src = torW + (p3 - 1) * 256 + j;
        else          src = legW + (2 * p3 + pm3 - 1) * 256 + j;
        u32x4 d;
        #pragma unroll
        for (int dd = 0; dd < 4; ++dd) {
            const int k = (k8 << 3) + 2 * dd;
            d[dd] = f2bfu(src[k * 4]) | (f2bfu(src[(k + 1) * 4]) << 16);
        }
        *(u32x4*)(wsw + 12288 + t2 * 4) = d;
    } else if (t < 3776) {                // encoder B-fragment
        const int t3 = t - 3520;
        const int lane = t3 & 63, ctl = t3 >> 6;
        const int col = (ctl << 4) + (lane & 15);
        const int kg = lane >> 4;
        auto encval = [&](int k) -> float {
            if (k < 8)   return Wt[k * 64 + col];
            if (k < 12)  return Wl[(k - 8) * 64 + col];
            if (k == 12) return bt[col];
            if (k == 13) return bl[col];
            return 0.f;
        };
        u32x4 d;
        #pragma unroll
        for (int dd = 0; dd < 4; ++dd) {
            const int k0 = kg * 8 + 2 * dd;
            d[dd] = f2bfu(encval(k0)) | (f2bfu(encval(k0 + 1)) << 16);
        }
        *(u32x4*)(wsw + 14080 + t3 * 4) = d;
    }
}

// ---------------------------------------------------------------------------
// Main: R12 AGG-free MFMA chain, GPB 8->16 (single variable vs R14).
// out = tanh(S*(h@Wrel) + h@Wroot + b); S constant A-fragment, U C-layout ==
// S-MFMA B-layout -> zero-LDS aggregation. LDS/graph 2KB, 32KB/block.
// 16 graphs amortize B-frag loads / setup / 8 barriers over 2x work and give
// 2x independent chains per wave for latency hiding. VGPR est ~110 under the
// (256,4) 128-cap; spill tripwire: WRITE_SIZE must stay ~7MB.
// ---------------------------------------------------------------------------
__global__ __launch_bounds__(THREADS, 4) void leg_main(
    const float* __restrict__ x,
    const float* __restrict__ gcb,
    const float* __restrict__ legB, const float* __restrict__ torB,
    const unsigned* __restrict__ wsw,
    float* __restrict__ out)
{
    __shared__ __align__(16) unsigned char smem[GPB * 2048];
    const int tid  = threadIdx.x;
    const int lane = tid & 63;
    const int ct   = tid >> 6;                 // wave id = col-tile
    const int g0   = blockIdx.x * GPB;

    const int bcol = (ct << 4) + (lane & 15);
    const float cb0 = gcb[bcol], cb1 = gcb[64 + bcol], cb2 = gcb[128 + bcol];

    // --- per-lane LDS byte offsets (2KB tiles: row stride 128B, 8 slots) ---
    const int row = lane & 15, kg = lane >> 4;
    const int voffA0 = row * 128 + (((kg ^ row) & 7) << 4);   // h k0-31
    const int voffA1 = voffA0 ^ 0x40;                         // h k32-63
    int voffC[4];
    #pragma unroll
    for (int r = 0; r < 4; ++r) {
        const int rr = (kg << 2) + r;
        voffC[r] = rr * 128 + (((((ct << 1) + ((lane >> 3) & 1)) ^ rr) & 7) << 4) + ((lane & 7) << 1);
    }

    // --- constant S' A-fragment from adjacency table (row 15 mask = 0) ---
    const unsigned sm = SMASK[row];
    union { u32x4 u; bf16x8 b; } sf;
    #pragma unroll
    for (int j2 = 0; j2 < 4; ++j2)
        sf.u[j2] = ((sm >> ((kg << 2) + j2)) & 1) ? 0x3F80u : 0u;  // bf16 1.0 at even k

// epilogue: tanh(acc[g]) -> bf16 -> LDS h (all 4 layers share)
#define EPI() do { \
    _Pragma("unroll") for (int g = 0; g < GPB; ++g) { \
        _Pragma("unroll") for (int r = 0; r < 4; ++r) { \
            const float tv = fast_tanh(acc[g][r]); \
            unsigned uu; CVTPK(uu, tv, tv); \
            *(unsigned short*)(smem + g * 2048 + voffC[r]) = (unsigned short)uu; \
        } } } while (0)

    // --- encoder (layer 0) as MFMA: A = [isT*x(8) | isL*x(0:4) | isT | isL] ---
    const int nmod3 = row - ((row * 11) >> 5) * 3;
    const bool nT = (nmod3 == 0);
    const unsigned mT = (nT && row < 15) ? 0xFFFFFFFFu : 0u;
    const unsigned mL = nT ? 0u : 0xFFFFFFFFu;
    const unsigned m01 = (kg == 0) ? mT : ((kg == 1) ? mL : 0u);
    const unsigned m45 = (kg == 0) ? mT : 0u;
    const unsigned c1213 = (kg == 1) ? ((mT ? 0x3F80u : 0u) | (mL ? 0x3F800000u : 0u)) : 0u;
    const int rowc = (row < 15) ? row : 0;
    const bf16x8 bfrE = *(const bf16x8*)(wsw + 14080 + tid * 4);

    f32x4 acc[GPB];
    #pragma unroll
    for (int g = 0; g < GPB; ++g) {
        const float4* xr = (const float4*)x + ((size_t)(g0 + g) * 15 + rowc) * 2;
        const float4 x0 = xr[0], x1 = xr[1];
        unsigned a01, a23, a45, a67;
        CVTPK(a01, x0.x, x0.y); CVTPK(a23, x0.z, x0.w);
        CVTPK(a45, x1.x, x1.y); CVTPK(a67, x1.z, x1.w);
        union { u32x4 u; bf16x8 b; } af;
        af.u[0] = a01 & m01;
        af.u[1] = a23 & m01;
        af.u[2] = (a45 & m45) | c1213;
        af.u[3] = a67 & m45;
        const f32x4 z = { 0.f, 0.f, 0.f, 0.f };
        acc[g] = __builtin_amdgcn_mfma_f32_16x16x32_bf16(af.b, bfrE, z, 0, 0, 0);
    }
    EPI();                   // waves write disjoint col-tiles
    __syncthreads();         // h0 visible to all waves' A-reads

    // --- 3x GraphConv: V = h@Wroot + b; U = h@Wrel; out = S'*U' + V ---
    #pragma unroll
    for (int it = 0; it < 3; ++it) {
        bf16x8 bfr[4];       // 0,1: Wroot k0-31,k32-63; 2,3: Wrel
        #pragma unroll
        for (int s = 0; s < 4; ++s)
            bfr[s] = *(const bf16x8*)(wsw + ((it * 4 + s) * 256 + tid) * 4);
        const float cbi = (it == 0) ? cb0 : (it == 1) ? cb1 : cb2;
        #pragma unroll
        for (int g = 0; g < GPB; ++g) {
            const unsigned char* sg = smem + g * 2048;
            const bf16x8 a0 = *(const bf16x8*)(sg + voffA0);
            const bf16x8 a1 = *(const bf16x8*)(sg + voffA1);
            f32x4 V = { cbi, cbi, cbi, cbi };
            V = __builtin_amdgcn_mfma_f32_16x16x32_bf16(a0, bfr[0], V, 0, 0, 0);
            V = __builtin_amdgcn_mfma_f32_16x16x32_bf16(a1, bfr[1], V, 0, 0, 0);
            const f32x4 z = { 0.f, 0.f, 0.f, 0.f };
            f32x4 U;
            U = __builtin_amdgcn_mfma_f32_16x16x32_bf16(a0, bfr[2], z, 0, 0, 0);
            U = __builtin_amdgcn_mfma_f32_16x16x32_bf16(a1, bfr[3], U, 0, 0, 0);
            // U' B-frag: k-slot kg*8+2r holds bf16(U[r]) low half, 0 high.
            union { u32x4 u; bf16x8 b; } ub;
            ub.u[0] = f2bfu(U[0]);
            ub.u[1] = f2bfu(U[1]);
            ub.u[2] = f2bfu(U[2]);
            ub.u[3] = f2bfu(U[3]);
            acc[g] = __builtin_amdgcn_mfma_f32_16x16x32_bf16(sf.b, ub.b, V, 0, 0, 0);
        }
        __syncthreads();     // all A-reads done before EPI overwrites h
        EPI();
        __syncthreads();     // new h visible
    }

    // --- heads: wave ct -> graphs 4ct..4ct+3; lane = (p,j) item ---
    // unpack-FMA path (proven). No raw-asm dot2 (R3/R4 lesson).
    if (lane < 56) {
        const int p = (lane >> 2) + 1, j = lane & 3;
        const int p3 = (p * 11) >> 5;
        const int pm3 = p - p3 * 3;
        float bias;
        if (pm3 == 0) bias = torB[((p3 - 1) << 2) + j];
        else          bias = legB[(((p3 << 1) + pm3 - 1) << 2) + j];
        const unsigned* wp = wsw + 12288 + (lane << 5);
        const int ps = (p & 7) << 4;
        #pragma unroll
        for (int gs = 0; gs < 4; ++gs) {
            const int g = (ct << 2) + gs;
            const unsigned char* hb = smem + g * 2048 + p * 128;
            float acch = 0.f;
            #pragma unroll
            for (int k8 = 0; k8 < 8; ++k8) {
                const u32x4 hv = *(const u32x4*)(hb + (ps ^ (k8 << 4)));
                const u32x4 wv = *(const u32x4*)(wp + (k8 << 2));
                #pragma unroll
                for (int dd = 0; dd < 4; ++dd) {
                    acch = __builtin_fmaf(lof(hv[dd]), lof(wv[dd]), acch);
                    acch = __builtin_fmaf(hif(hv[dd]), hif(wv[dd]), acch);
                }
            }
            acch += bias;
            const int mloc = ((p - 1) << 1) + (j >> 1);
            const size_t ob = (size_t)(g0 + g) * 28 + mloc;
            if ((j & 1) == 0) {
                out[ob] = acch;
            } else {
                const float z = acch + BIAS_SP;
                const float sp = (z > 15.f) ? z : __logf(1.f + __expf(z));
                out[(size_t)NB * 28 + ob] = fmaxf(sp, 1e-4f);
            }
        }
    }
}

extern "C" void kernel_launch(void* const* d_in, const int* in_sizes, int n_in,
                              void* d_out, int out_size, void* d_ws, size_t ws_size,
                              hipStream_t stream) {
    (void)in_sizes; (void)n_in; (void)out_size; (void)ws_size;
    const float* x     = (const float*)d_in[0];
    // d_in[1] = edge_index (fixed template, unused), d_in[2] = batch_size
    const float* Wt    = (const float*)d_in[3];
    const float* bt    = (const float*)d_in[4];
    const float* Wl    = (const float*)d_in[5];
    const float* bl    = (const float*)d_in[6];
    const float* Wroot = (const float*)d_in[7];
    const float* Wrel  = (const float*)d_in[8];
    const float* gcb   = (const float*)d_in[9];
    const float* legW  = (const float*)d_in[10];
    const float* legB  = (const float*)d_in[11];
    const float* torW  = (const float*)d_in[12];
    const float* torB  = (const float*)d_in[13];
    unsigned* wsw = (unsigned*)d_ws;           // needs 60416 B of scratch
    setup_kernel<<<15, 256, 0, stream>>>(Wroot, Wrel, legW, torW, Wt, bt, Wl, bl, wsw);
    leg_main<<<NB / GPB, THREADS, 0, stream>>>(x, gcb, legB, torB, wsw, (float*)d_out);
}